// Round 16
// baseline (286.354 us; speedup 1.0000x reference)
//
#include <hip/hip_runtime.h>
#include <hip/hip_bf16.h>

#define Hn 224
#define HWn (224*224)
#define B_ 16
#define CIN_ 64
#define COUT_ 64
#define PR 230            // padded rows: 2 top + 224 + 4 bottom
#define PC 240            // padded row stride in floats
#define PHW (PR*PC)
#define GUARD 1024        // floats of guard before Sp
#define WOFF  (4*1024*1024)  // byte offset of W' in d_ws
#define CTROFF (8*1024*1024) // byte offset of counters in d_ws
#define NK1   1792        // k1 items: 112 per image (2 rows each)
#define NCONV 1792        // conv items: 112 per image (2 rows each)
#define DONE_TGT 112

typedef __attribute__((ext_vector_type(4)))  float f32x4;
typedef __attribute__((ext_vector_type(8)))  short bf16x8;
typedef __attribute__((ext_vector_type(16))) float f32x16;

// Wprep: W'[oc][ky*8+kx] = bf16(K[oc,0,ky,kx]), zero at kx==7 / ky==7.
__global__ __launch_bounds__(256) void wprep_kernel(const float* __restrict__ K,
                                                    unsigned short* __restrict__ W) {
    int i = blockIdx.x * 256 + threadIdx.x;
    if (i >= 64 * 64) return;
    int oc = i >> 6, kk = i & 63;
    int ky = kk >> 3, kx = kk & 7;
    float v = (ky < 7 && kx < 7) ? K[(size_t)oc * (CIN_ * 49) + ky * 7 + kx] : 0.0f;
    __hip_bfloat16 h = __float2bfloat16(v);
    W[i] = *(unsigned short*)&h;
}

// One k1 unit: 4 pixels (y, x0=q*4) of image b: 64-ch nt-sum + padded store + halos.
__device__ __forceinline__ void k1_unit(const float* __restrict__ x,
                                        float* __restrict__ Sb, int b, int y, int q) {
    const int s4 = HWn / 4;
    const f32x4* xb = (const f32x4*)x + (size_t)b * CIN_ * s4 + (y * 56 + q);

    f32x4 a0 = __builtin_nontemporal_load(xb + 0 * s4);
    f32x4 a1 = __builtin_nontemporal_load(xb + 1 * s4);
    f32x4 a2 = __builtin_nontemporal_load(xb + 2 * s4);
    f32x4 a3 = __builtin_nontemporal_load(xb + 3 * s4);
    #pragma unroll 4
    for (int c = 4; c < CIN_; c += 4) {
        a0 += __builtin_nontemporal_load(xb + (size_t)(c + 0) * s4);
        a1 += __builtin_nontemporal_load(xb + (size_t)(c + 1) * s4);
        a2 += __builtin_nontemporal_load(xb + (size_t)(c + 2) * s4);
        a3 += __builtin_nontemporal_load(xb + (size_t)(c + 3) * s4);
    }
    f32x4 r = (a0 + a1) + (a2 + a3);
    float v0 = r.x, v1 = r.y, v2 = r.z, v3 = r.w;
    const int x0 = q * 4;

    float* dst = Sb + (size_t)(y + 2) * PC + 2 + x0;
    dst[0] = v0; dst[1] = v1; dst[2] = v2; dst[3] = v3;

    if (y < 4) {
        float* d = Sb + (size_t)(y + 226) * PC + 2 + x0;
        d[0] = v0; d[1] = v1; d[2] = v2; d[3] = v3;
    }
    if (y >= 222) {
        float* d = Sb + (size_t)(y - 222) * PC + 2 + x0;
        d[0] = v0; d[1] = v1; d[2] = v2; d[3] = v3;
    }
    if (x0 == 0) {
        float* d = Sb + (size_t)(y + 2) * PC + 226;
        d[0] = v0; d[1] = v1; d[2] = v2; d[3] = v3;
        if (y < 4) {
            float* e = Sb + (size_t)(y + 226) * PC + 226;
            e[0] = v0; e[1] = v1; e[2] = v2; e[3] = v3;
        }
        if (y >= 222) {
            float* e = Sb + (size_t)(y - 222) * PC + 226;
            e[0] = v0; e[1] = v1; e[2] = v2; e[3] = v3;
        }
    }
    if (x0 == 220) {
        float* d = Sb + (size_t)(y + 2) * PC;
        d[0] = v2; d[1] = v3;
        if (y < 4) {
            float* e = Sb + (size_t)(y + 226) * PC;
            e[0] = v2; e[1] = v3;
        }
        if (y >= 222) {
            float* e = Sb + (size_t)(y - 222) * PC;
            e[0] = v2; e[1] = v3;
        }
    }
}

// One conv item: 2 output rows (y = yg*2 + wave) x 64 oc of image b (R7/R12 body).
__device__ __forceinline__ void conv_item(const float* __restrict__ Sp,
                                          const unsigned short* __restrict__ W,
                                          float* __restrict__ out, int b, int yg) {
    const int wv = threadIdx.x >> 6;
    const int l  = threadIdx.x & 63;
    const int y   = yg * 2 + wv;
    const int lo5 = l & 31;
    const int hi  = l >> 5;

    bf16x8 afrag[2][4];
    #pragma unroll
    for (int g = 0; g < 2; ++g)
        #pragma unroll
        for (int c = 0; c < 4; ++c)
            afrag[g][c] = *(const bf16x8*)(W + ((g * 32 + lo5) * 64 + c * 16 + hi * 8));

    const float* Sb = Sp + (size_t)b * PHW;
    float* outb = out + (size_t)b * COUT_ * HWn + (size_t)y * Hn;

    for (int xt = 0; xt < 7; ++xt) {
        const int x0 = xt * 32;
        f32x16 acc0, acc1;
        #pragma unroll
        for (int i = 0; i < 16; ++i) { acc0[i] = 0.0f; acc1[i] = 0.0f; }

        #pragma unroll
        for (int c = 0; c < 4; ++c) {
            const int rowg = y + 6 - (2 * c + hi);
            const float* rp = Sb + rowg * PC + x0 + 6 + lo5;
            union { int i[4]; bf16x8 v; } bu;
            #pragma unroll
            for (int j = 0; j < 4; ++j) {
                float flo = rp[-(2 * j)];
                float fhi = rp[-(2 * j) - 1];
                asm("v_cvt_pk_bf16_f32 %0, %1, %2" : "=v"(bu.i[j]) : "v"(flo), "v"(fhi));
            }
            acc0 = __builtin_amdgcn_mfma_f32_32x32x16_bf16(afrag[0][c], bu.v, acc0, 0, 0, 0);
            acc1 = __builtin_amdgcn_mfma_f32_32x32x16_bf16(afrag[1][c], bu.v, acc1, 0, 0, 0);
        }

        #pragma unroll
        for (int r = 0; r < 16; ++r) {
            const int row = (r & 3) + 8 * (r >> 2) + 4 * hi;
            outb[(size_t)row        * HWn + x0 + lo5] = acc0[r];
            outb[(size_t)(32 + row) * HWn + x0 + lo5] = acc1[r];
        }
    }
}

// Fused producer-consumer: work-steal k1 items (image-major), then conv items
// (image-major) gated on per-image done counters. Overlaps the 205MB read
// stream (k1) with the 205MB(+writeback) write stream (conv).
__global__ __launch_bounds__(128, 2) void fused_kernel(const float* __restrict__ x,
                                                       const unsigned short* __restrict__ W,
                                                       float* __restrict__ Sp,
                                                       float* __restrict__ out,
                                                       int* __restrict__ ctrs) {
    __shared__ int sI;
    int* k1c   = ctrs + 0;
    int* convc = ctrs + 1;
    int* done  = ctrs + 2;      // [16]

    // ---- producer phase: claim k1 items until exhausted ----
    for (;;) {
        __syncthreads();
        if (threadIdx.x == 0) sI = atomicAdd(k1c, 1);
        __syncthreads();
        int i = sI;
        if (i >= NK1) break;
        int b = i / 112, r = i - b * 112;
        float* Sb = Sp + (size_t)b * PHW;
        int t = threadIdx.x;
        if (t < 112) k1_unit(x, Sb, b, r * 2 + t / 56, t % 56);
        __syncthreads();                     // drains stores (vmcnt0 before barrier)
        if (threadIdx.x == 0) {
            __threadfence();                 // device-scope: flush L2 for cross-XCD readers
            __hip_atomic_fetch_add(&done[b], 1, __ATOMIC_RELEASE, __HIP_MEMORY_SCOPE_AGENT);
        }
    }

    // ---- consumer phase: claim conv items, gated per image ----
    for (;;) {
        __syncthreads();
        if (threadIdx.x == 0) sI = atomicAdd(convc, 1);
        __syncthreads();
        int j = sI;
        if (j >= NCONV) break;
        int b = j / 112, yg = j - b * 112;
        if (threadIdx.x == 0) {
            int spin = 0;
            while (__hip_atomic_load(&done[b], __ATOMIC_ACQUIRE,
                                     __HIP_MEMORY_SCOPE_AGENT) < DONE_TGT) {
                __builtin_amdgcn_s_sleep(8);
                if (++spin > 2000000) break;   // failsafe: never hang the harness
            }
        }
        __syncthreads();
        conv_item(Sp, W, out, b, yg);
    }
}

extern "C" void kernel_launch(void* const* d_in, const int* in_sizes, int n_in,
                              void* d_out, int out_size, void* d_ws, size_t ws_size,
                              hipStream_t stream) {
    const float* x = (const float*)d_in[0];   // [16,64,224,224] f32
    const float* K = (const float*)d_in[1];   // [64,64,7,7] f32
    float* out = (float*)d_out;               // [16,64,224,224] f32
    float* Sp = (float*)d_ws + GUARD;         // padded S' with guard
    unsigned short* W = (unsigned short*)((char*)d_ws + WOFF);
    int* ctrs = (int*)((char*)d_ws + CTROFF); // k1_ctr, conv_ctr, done[16]

    hipMemsetAsync(ctrs, 0, 256, stream);
    wprep_kernel<<<16, 256, 0, stream>>>(K, W);
    fused_kernel<<<1024, 128, 0, stream>>>(x, W, Sp, out, ctrs);
}

// Round 17
// 90.926 us; speedup vs baseline: 3.1493x; 3.1493x over previous
//
#include <hip/hip_runtime.h>
#include <hip/hip_bf16.h>

#define Hn 224
#define HWn (224*224)
#define B_ 16
#define CIN_ 64
#define COUT_ 64
#define PR 230            // padded rows: 2 top + 224 + 4 bottom
#define PC 240            // padded row stride in floats
#define PHW (PR*PC)
#define GUARD 1024        // floats of guard before Sp
#define WOFF (4*1024*1024) // byte offset of W' in d_ws

typedef __attribute__((ext_vector_type(4)))  float f32x4;
typedef __attribute__((ext_vector_type(8)))  short bf16x8;
typedef __attribute__((ext_vector_type(16))) float f32x16;

// Kernel 1: S'[b, y+2, x+2] = sum_ic x[b,ic,y,x]  (padded f32 layout)
// + inline halo replication. x loads NON-TEMPORAL (R12 win: x never evicts
// the dirty out lines that stay L3-resident across replays).
__global__ __launch_bounds__(256) void chan_sum_kernel(const float* __restrict__ x,
                                                       float* __restrict__ Sp) {
    int idx = blockIdx.x * 256 + threadIdx.x;
    const int npix4 = B_ * HWn / 4;
    if (idx >= npix4) return;
    const int s4 = HWn / 4;
    int b  = idx / s4;
    int p4 = idx - b * s4;
    const f32x4* xb = (const f32x4*)x + (size_t)b * CIN_ * s4 + p4;

    f32x4 a0 = __builtin_nontemporal_load(xb + 0 * s4);
    f32x4 a1 = __builtin_nontemporal_load(xb + 1 * s4);
    f32x4 a2 = __builtin_nontemporal_load(xb + 2 * s4);
    f32x4 a3 = __builtin_nontemporal_load(xb + 3 * s4);
    #pragma unroll 4
    for (int c = 4; c < CIN_; c += 4) {
        a0 += __builtin_nontemporal_load(xb + (size_t)(c + 0) * s4);
        a1 += __builtin_nontemporal_load(xb + (size_t)(c + 1) * s4);
        a2 += __builtin_nontemporal_load(xb + (size_t)(c + 2) * s4);
        a3 += __builtin_nontemporal_load(xb + (size_t)(c + 3) * s4);
    }
    f32x4 r = (a0 + a1) + (a2 + a3);
    float v0 = r.x, v1 = r.y, v2 = r.z, v3 = r.w;

    int y  = p4 / 56;                 // 0..223
    int x0 = (p4 - y * 56) * 4;       // 0..220 step 4
    float* Sb = Sp + (size_t)b * PHW;

    float* dst = Sb + (size_t)(y + 2) * PC + 2 + x0;
    dst[0] = v0; dst[1] = v1; dst[2] = v2; dst[3] = v3;

    if (y < 4) {
        float* d = Sb + (size_t)(y + 226) * PC + 2 + x0;
        d[0] = v0; d[1] = v1; d[2] = v2; d[3] = v3;
    }
    if (y >= 222) {
        float* d = Sb + (size_t)(y - 222) * PC + 2 + x0;
        d[0] = v0; d[1] = v1; d[2] = v2; d[3] = v3;
    }
    if (x0 == 0) {
        float* d = Sb + (size_t)(y + 2) * PC + 226;
        d[0] = v0; d[1] = v1; d[2] = v2; d[3] = v3;
        if (y < 4) {
            float* e = Sb + (size_t)(y + 226) * PC + 226;
            e[0] = v0; e[1] = v1; e[2] = v2; e[3] = v3;
        }
        if (y >= 222) {
            float* e = Sb + (size_t)(y - 222) * PC + 226;
            e[0] = v0; e[1] = v1; e[2] = v2; e[3] = v3;
        }
    }
    if (x0 == 220) {                   // x 222,223 live in lanes v2,v3
        float* d = Sb + (size_t)(y + 2) * PC;
        d[0] = v2; d[1] = v3;
        if (y < 4) {
            float* e = Sb + (size_t)(y + 226) * PC;
            e[0] = v2; e[1] = v3;
        }
        if (y >= 222) {
            float* e = Sb + (size_t)(y - 222) * PC;
            e[0] = v2; e[1] = v3;
        }
    }
}

// Wprep: W'[oc][ky*8+kx] = bf16(K[oc,0,ky,kx]), zero at kx==7 / ky==7.
__global__ __launch_bounds__(256) void wprep_kernel(const float* __restrict__ K,
                                                    unsigned short* __restrict__ W) {
    int i = blockIdx.x * 256 + threadIdx.x;
    if (i >= 64 * 64) return;
    int oc = i >> 6, kk = i & 63;
    int ky = kk >> 3, kx = kk & 7;
    float v = (ky < 7 && kx < 7) ? K[(size_t)oc * (CIN_ * 49) + ky * 7 + kx] : 0.0f;
    __hip_bfloat16 h = __float2bfloat16(v);
    W[i] = *(unsigned short*)&h;
}

// Conv via MFMA (R12-verified body), W' from wprep (lean 8-load prologue).
// __launch_bounds__(128,6): 24 waves/CU (1.5x) to hide Sp L2/L3 load latency.
__global__ __launch_bounds__(128, 6) void conv_mfma(const float* __restrict__ Sp,
                                                    const unsigned short* __restrict__ W,
                                                    float* __restrict__ out) {
    const int yg = blockIdx.x;           // 0..111
    const int b  = blockIdx.y;           // 0..15
    const int wv = threadIdx.x >> 6;     // 0..1
    const int l  = threadIdx.x & 63;
    const int y   = yg * 2 + wv;
    const int lo5 = l & 31;
    const int hi  = l >> 5;

    // A fragments: lane holds A[m=lo5][k = c*16 + hi*8 + j], j=0..7 (16B each)
    bf16x8 afrag[2][4];
    #pragma unroll
    for (int g = 0; g < 2; ++g)
        #pragma unroll
        for (int c = 0; c < 4; ++c)
            afrag[g][c] = *(const bf16x8*)(W + ((g * 32 + lo5) * 64 + c * 16 + hi * 8));

    const float* Sb = Sp + (size_t)b * PHW;
    float* outb = out + (size_t)b * COUT_ * HWn + (size_t)y * Hn;

    for (int xt = 0; xt < 7; ++xt) {
        const int x0 = xt * 32;

        f32x16 acc0, acc1;
        #pragma unroll
        for (int i = 0; i < 16; ++i) { acc0[i] = 0.0f; acc1[i] = 0.0f; }

        #pragma unroll
        for (int c = 0; c < 4; ++c) {
            // B fragment: lane holds B^T[n=lo5][k = c*16 + hi*8 + 2j + {0,1}]
            const int rowg = y + 6 - (2 * c + hi);
            const float* rp = Sb + rowg * PC + x0 + 6 + lo5;
            union { int i[4]; bf16x8 v; } bu;
            #pragma unroll
            for (int j = 0; j < 4; ++j) {
                float flo = rp[-(2 * j)];        // kx = 2j
                float fhi = rp[-(2 * j) - 1];    // kx = 2j+1
                asm("v_cvt_pk_bf16_f32 %0, %1, %2" : "=v"(bu.i[j]) : "v"(flo), "v"(fhi));
            }
            acc0 = __builtin_amdgcn_mfma_f32_32x32x16_bf16(afrag[0][c], bu.v, acc0, 0, 0, 0);
            acc1 = __builtin_amdgcn_mfma_f32_32x32x16_bf16(afrag[1][c], bu.v, acc1, 0, 0, 0);
        }

        // C/D layout: col = lo5 (pixel), row = (r&3) + 8*(r>>2) + 4*hi (oc)
        #pragma unroll
        for (int r = 0; r < 16; ++r) {
            const int row = (r & 3) + 8 * (r >> 2) + 4 * hi;
            outb[(size_t)row        * HWn + x0 + lo5] = acc0[r];
            outb[(size_t)(32 + row) * HWn + x0 + lo5] = acc1[r];
        }
    }
}

extern "C" void kernel_launch(void* const* d_in, const int* in_sizes, int n_in,
                              void* d_out, int out_size, void* d_ws, size_t ws_size,
                              hipStream_t stream) {
    const float* x = (const float*)d_in[0];   // [16,64,224,224] f32
    const float* K = (const float*)d_in[1];   // [64,64,7,7] f32
    float* out = (float*)d_out;               // [16,64,224,224] f32
    float* Sp = (float*)d_ws + GUARD;         // padded S' with guard
    unsigned short* W = (unsigned short*)((char*)d_ws + WOFF);

    const int npix4 = B_ * HWn / 4;
    chan_sum_kernel<<<(npix4 + 255) / 256, 256, 0, stream>>>(x, Sp);

    wprep_kernel<<<16, 256, 0, stream>>>(K, W);

    dim3 g2(112, 16);
    conv_mfma<<<g2, 128, 0, stream>>>(Sp, W, out);
}

// Round 18
// 87.702 us; speedup vs baseline: 3.2651x; 1.0368x over previous
//
#include <hip/hip_runtime.h>
#include <hip/hip_bf16.h>

#define Hn 224
#define HWn (224*224)
#define B_ 16
#define CIN_ 64
#define COUT_ 64
#define PR 230            // padded rows: 2 top + 224 + 4 bottom
#define PC 240            // padded row stride in floats
#define PHW (PR*PC)
#define GUARD 1024        // floats of guard before Sp
#define WOFF (4*1024*1024) // byte offset of Wpk in d_ws

typedef __attribute__((ext_vector_type(4)))  float f32x4;
typedef __attribute__((ext_vector_type(8)))  short bf16x8;
typedef __attribute__((ext_vector_type(16))) float f32x16;

// Kernel 1: S'[b, y+2, x+2] = sum_ic x[b,ic,y,x]  (padded f32 layout)
// + inline halo replication. x loads NON-TEMPORAL (R12 win).
__global__ __launch_bounds__(256) void chan_sum_kernel(const float* __restrict__ x,
                                                       float* __restrict__ Sp) {
    int idx = blockIdx.x * 256 + threadIdx.x;
    const int npix4 = B_ * HWn / 4;
    if (idx >= npix4) return;
    const int s4 = HWn / 4;
    int b  = idx / s4;
    int p4 = idx - b * s4;
    const f32x4* xb = (const f32x4*)x + (size_t)b * CIN_ * s4 + p4;

    f32x4 a0 = __builtin_nontemporal_load(xb + 0 * s4);
    f32x4 a1 = __builtin_nontemporal_load(xb + 1 * s4);
    f32x4 a2 = __builtin_nontemporal_load(xb + 2 * s4);
    f32x4 a3 = __builtin_nontemporal_load(xb + 3 * s4);
    #pragma unroll 4
    for (int c = 4; c < CIN_; c += 4) {
        a0 += __builtin_nontemporal_load(xb + (size_t)(c + 0) * s4);
        a1 += __builtin_nontemporal_load(xb + (size_t)(c + 1) * s4);
        a2 += __builtin_nontemporal_load(xb + (size_t)(c + 2) * s4);
        a3 += __builtin_nontemporal_load(xb + (size_t)(c + 3) * s4);
    }
    f32x4 r = (a0 + a1) + (a2 + a3);
    float v0 = r.x, v1 = r.y, v2 = r.z, v3 = r.w;

    int y  = p4 / 56;                 // 0..223
    int x0 = (p4 - y * 56) * 4;       // 0..220 step 4
    float* Sb = Sp + (size_t)b * PHW;

    float* dst = Sb + (size_t)(y + 2) * PC + 2 + x0;
    dst[0] = v0; dst[1] = v1; dst[2] = v2; dst[3] = v3;

    if (y < 4) {
        float* d = Sb + (size_t)(y + 226) * PC + 2 + x0;
        d[0] = v0; d[1] = v1; d[2] = v2; d[3] = v3;
    }
    if (y >= 222) {
        float* d = Sb + (size_t)(y - 222) * PC + 2 + x0;
        d[0] = v0; d[1] = v1; d[2] = v2; d[3] = v3;
    }
    if (x0 == 0) {
        float* d = Sb + (size_t)(y + 2) * PC + 226;
        d[0] = v0; d[1] = v1; d[2] = v2; d[3] = v3;
        if (y < 4) {
            float* e = Sb + (size_t)(y + 226) * PC + 226;
            e[0] = v0; e[1] = v1; e[2] = v2; e[3] = v3;
        }
        if (y >= 222) {
            float* e = Sb + (size_t)(y - 222) * PC + 226;
            e[0] = v0; e[1] = v1; e[2] = v2; e[3] = v3;
        }
    }
    if (x0 == 220) {                   // x 222,223 live in lanes v2,v3
        float* d = Sb + (size_t)(y + 2) * PC;
        d[0] = v2; d[1] = v3;
        if (y < 4) {
            float* e = Sb + (size_t)(y + 226) * PC;
            e[0] = v2; e[1] = v3;
        }
        if (y >= 222) {
            float* e = Sb + (size_t)(y - 222) * PC;
            e[0] = v2; e[1] = v3;
        }
    }
}

// Wprep: fragment-ordered B-operand weights.
// Wpk[g][ch][lane][e] = bf16(K[oc = g*32+lane][0][ky = ch][kx = e]),
// zero at e==7 or ch==7.  (4096 bf16 = 8 KB)
__global__ __launch_bounds__(256) void wprep_kernel(const float* __restrict__ K,
                                                    unsigned short* __restrict__ Wpk) {
    int i = blockIdx.x * 256 + threadIdx.x;
    if (i >= 4096) return;
    int e    = i & 7;
    int lane = (i >> 3) & 31;
    int ch   = (i >> 8) & 7;          // ky
    int g    = i >> 11;
    int oc   = g * 32 + lane;
    float v = (ch < 7 && e < 7) ? K[(size_t)oc * (CIN_ * 49) + ch * 7 + e] : 0.0f;
    __hip_bfloat16 h = __float2bfloat16(v);
    Wpk[i] = *(unsigned short*)&h;
}

// Conv via MFMA, OPERAND-SWAPPED: A = patch (rows = pixels), B = W (cols = oc).
// D: col=lane&31 -> oc, row r -> pixel (r&3)+8*(r>>2)+4*hi -> each lane's
// acc quad [4q..4q+3] = 4 consecutive pixels -> global_store_dwordx4.
// Stores per thread: 224 dword -> 56 dwordx4.
__global__ __launch_bounds__(128, 4) void conv_mfma(const float* __restrict__ Sp,
                                                    const unsigned short* __restrict__ Wpk,
                                                    float* __restrict__ out) {
    const int yg = blockIdx.x;           // 0..111
    const int b  = blockIdx.y;           // 0..15
    const int wv = threadIdx.x >> 6;     // 0..1
    const int l  = threadIdx.x & 63;
    const int y   = yg * 2 + wv;
    const int lo5 = l & 31;
    const int hi  = l >> 5;

    // B fragments (weights): lane holds B[k=c*16+hi*8+e][oc=g*32+lo5], e=0..7.
    bf16x8 bfrag[2][4];
    #pragma unroll
    for (int g = 0; g < 2; ++g)
        #pragma unroll
        for (int c = 0; c < 4; ++c)
            bfrag[g][c] = *(const bf16x8*)(Wpk + ((size_t)(g * 8 + c * 2 + hi) * 32 + lo5) * 8);

    const float* Sb = Sp + (size_t)b * PHW;
    float* outb = out + (size_t)b * COUT_ * HWn + (size_t)y * Hn;

    for (int xt = 0; xt < 7; ++xt) {
        const int x0 = xt * 32;

        f32x16 acc0, acc1;
        #pragma unroll
        for (int i = 0; i < 16; ++i) { acc0[i] = 0.0f; acc1[i] = 0.0f; }

        #pragma unroll
        for (int c = 0; c < 4; ++c) {
            // A fragment (patch): lane holds A[m=lo5 (pixel)][k=c*16+hi*8+e],
            // e=kx, ky=2c+hi. Same per-lane data as the pre-swap B fragment.
            const int rowg = y + 6 - (2 * c + hi);
            const float* rp = Sb + rowg * PC + x0 + 6 + lo5;
            union { int i[4]; bf16x8 v; } au;
            #pragma unroll
            for (int j = 0; j < 4; ++j) {
                float flo = rp[-(2 * j)];        // kx = 2j
                float fhi = rp[-(2 * j) - 1];    // kx = 2j+1
                asm("v_cvt_pk_bf16_f32 %0, %1, %2" : "=v"(au.i[j]) : "v"(flo), "v"(fhi));
            }
            acc0 = __builtin_amdgcn_mfma_f32_32x32x16_bf16(au.v, bfrag[0][c], acc0, 0, 0, 0);
            acc1 = __builtin_amdgcn_mfma_f32_32x32x16_bf16(au.v, bfrag[1][c], acc1, 0, 0, 0);
        }

        // D: col=lo5 -> oc, row=(r&3)+8*(r>>2)+4*hi -> pixel. Quad stores.
        float* p0 = outb + (size_t)lo5        * HWn + x0 + 4 * hi;
        float* p1 = outb + (size_t)(32 + lo5) * HWn + x0 + 4 * hi;
        #pragma unroll
        for (int q = 0; q < 4; ++q) {
            f32x4 v0 = { acc0[4*q+0], acc0[4*q+1], acc0[4*q+2], acc0[4*q+3] };
            f32x4 v1 = { acc1[4*q+0], acc1[4*q+1], acc1[4*q+2], acc1[4*q+3] };
            *(f32x4*)(p0 + 8 * q) = v0;
            *(f32x4*)(p1 + 8 * q) = v1;
        }
    }
}

extern "C" void kernel_launch(void* const* d_in, const int* in_sizes, int n_in,
                              void* d_out, int out_size, void* d_ws, size_t ws_size,
                              hipStream_t stream) {
    const float* x = (const float*)d_in[0];   // [16,64,224,224] f32
    const float* K = (const float*)d_in[1];   // [64,64,7,7] f32
    float* out = (float*)d_out;               // [16,64,224,224] f32
    float* Sp = (float*)d_ws + GUARD;         // padded S' with guard
    unsigned short* Wpk = (unsigned short*)((char*)d_ws + WOFF);

    const int npix4 = B_ * HWn / 4;
    chan_sum_kernel<<<(npix4 + 255) / 256, 256, 0, stream>>>(x, Sp);

    wprep_kernel<<<16, 256, 0, stream>>>(K, Wpk);

    dim3 g2(112, 16);
    conv_mfma<<<g2, 128, 0, stream>>>(Sp, Wpk, out);
}

// Round 19
// 79.025 us; speedup vs baseline: 3.6236x; 1.1098x over previous
//
#include <hip/hip_runtime.h>
#include <hip/hip_bf16.h>

#define Hn 224
#define HWn (224*224)
#define B_ 16
#define CIN_ 64
#define COUT_ 64
#define PR 230            // padded rows: 2 top + 224 + 4 bottom
#define PC 240            // padded row stride in floats
#define PHW (PR*PC)
#define GUARD 1024        // floats of guard before Sp (covers row -1 reads)
#define WOFF (4*1024*1024) // byte offset of W' in d_ws

typedef __attribute__((ext_vector_type(4)))  float f32x4;
typedef __attribute__((ext_vector_type(8)))  short bf16x8;
typedef __attribute__((ext_vector_type(16))) float f32x16;

// Kernel 1: S'[b, y+2, x+2] = sum_ic x[b,ic,y,x]  (padded f32 layout)
// + inline halo replication. x loads NON-TEMPORAL (R12 win).
__global__ __launch_bounds__(256) void chan_sum_kernel(const float* __restrict__ x,
                                                       float* __restrict__ Sp) {
    int idx = blockIdx.x * 256 + threadIdx.x;
    const int npix4 = B_ * HWn / 4;
    if (idx >= npix4) return;
    const int s4 = HWn / 4;
    int b  = idx / s4;
    int p4 = idx - b * s4;
    const f32x4* xb = (const f32x4*)x + (size_t)b * CIN_ * s4 + p4;

    f32x4 a0 = __builtin_nontemporal_load(xb + 0 * s4);
    f32x4 a1 = __builtin_nontemporal_load(xb + 1 * s4);
    f32x4 a2 = __builtin_nontemporal_load(xb + 2 * s4);
    f32x4 a3 = __builtin_nontemporal_load(xb + 3 * s4);
    #pragma unroll 4
    for (int c = 4; c < CIN_; c += 4) {
        a0 += __builtin_nontemporal_load(xb + (size_t)(c + 0) * s4);
        a1 += __builtin_nontemporal_load(xb + (size_t)(c + 1) * s4);
        a2 += __builtin_nontemporal_load(xb + (size_t)(c + 2) * s4);
        a3 += __builtin_nontemporal_load(xb + (size_t)(c + 3) * s4);
    }
    f32x4 r = (a0 + a1) + (a2 + a3);
    float v0 = r.x, v1 = r.y, v2 = r.z, v3 = r.w;

    int y  = p4 / 56;                 // 0..223
    int x0 = (p4 - y * 56) * 4;       // 0..220 step 4
    float* Sb = Sp + (size_t)b * PHW;

    float* dst = Sb + (size_t)(y + 2) * PC + 2 + x0;
    dst[0] = v0; dst[1] = v1; dst[2] = v2; dst[3] = v3;

    if (y < 4) {
        float* d = Sb + (size_t)(y + 226) * PC + 2 + x0;
        d[0] = v0; d[1] = v1; d[2] = v2; d[3] = v3;
    }
    if (y >= 222) {
        float* d = Sb + (size_t)(y - 222) * PC + 2 + x0;
        d[0] = v0; d[1] = v1; d[2] = v2; d[3] = v3;
    }
    if (x0 == 0) {
        float* d = Sb + (size_t)(y + 2) * PC + 226;
        d[0] = v0; d[1] = v1; d[2] = v2; d[3] = v3;
        if (y < 4) {
            float* e = Sb + (size_t)(y + 226) * PC + 226;
            e[0] = v0; e[1] = v1; e[2] = v2; e[3] = v3;
        }
        if (y >= 222) {
            float* e = Sb + (size_t)(y - 222) * PC + 226;
            e[0] = v0; e[1] = v1; e[2] = v2; e[3] = v3;
        }
    }
    if (x0 == 220) {                   // x 222,223 live in lanes v2,v3
        float* d = Sb + (size_t)(y + 2) * PC;
        d[0] = v2; d[1] = v3;
        if (y < 4) {
            float* e = Sb + (size_t)(y + 226) * PC;
            e[0] = v2; e[1] = v3;
        }
        if (y >= 222) {
            float* e = Sb + (size_t)(y - 222) * PC;
            e[0] = v2; e[1] = v3;
        }
    }
}

// Wprep: W'[oc][ky*8+kx] = bf16(K[oc,0,ky,kx]), zero at kx==7 / ky==7.
__global__ __launch_bounds__(256) void wprep_kernel(const float* __restrict__ K,
                                                    unsigned short* __restrict__ W) {
    int i = blockIdx.x * 256 + threadIdx.x;
    if (i >= 64 * 64) return;
    int oc = i >> 6, kk = i & 63;
    int ky = kk >> 3, kx = kk & 7;
    float v = (ky < 7 && kx < 7) ? K[(size_t)oc * (CIN_ * 49) + ky * 7 + kx] : 0.0f;
    __hip_bfloat16 h = __float2bfloat16(v);
    W[i] = *(unsigned short*)&h;
}

// Conv via MFMA — R12 body + LDS-staged patch rows.
// Block (yg,b) stages padded rows yg*2-1 .. yg*2+7 (9 rows x 240 f32) into
// LDS with 540 independent dwordx4 loads (one vmcnt drain), then the xt loop
// builds B-fragments from ds_read instead of scattered L2 round-trips.
__global__ __launch_bounds__(128, 4) void conv_mfma(const float* __restrict__ Sp,
                                                    const unsigned short* __restrict__ W,
                                                    float* __restrict__ out) {
    __shared__ float sS[9 * PC];         // 8.64 KB

    const int yg = blockIdx.x;           // 0..111
    const int b  = blockIdx.y;           // 0..15
    const int wv = threadIdx.x >> 6;     // 0..1
    const int l  = threadIdx.x & 63;
    const int y   = yg * 2 + wv;
    const int lo5 = l & 31;
    const int hi  = l >> 5;

    // stage 9 rows (row -1 falls in the guard for yg==0: garbage x zero weight)
    {
        const float* src = Sp + (size_t)b * PHW + (size_t)(yg * 2 - 1) * PC;
        for (int i = threadIdx.x; i < 9 * (PC / 4); i += 128) {
            int r = i / (PC / 4), c4 = i - r * (PC / 4);
            *(f32x4*)&sS[r * PC + c4 * 4] =
                *(const f32x4*)(src + (size_t)r * PC + c4 * 4);
        }
    }

    // A fragments: lane holds A[m=lo5][k = c*16 + hi*8 + j], j=0..7 (16B each)
    bf16x8 afrag[2][4];
    #pragma unroll
    for (int g = 0; g < 2; ++g)
        #pragma unroll
        for (int c = 0; c < 4; ++c)
            afrag[g][c] = *(const bf16x8*)(W + ((g * 32 + lo5) * 64 + c * 16 + hi * 8));

    __syncthreads();

    float* outb = out + (size_t)b * COUT_ * HWn + (size_t)y * Hn;

    for (int xt = 0; xt < 7; ++xt) {
        const int x0 = xt * 32;

        f32x16 acc0, acc1;
        #pragma unroll
        for (int i = 0; i < 16; ++i) { acc0[i] = 0.0f; acc1[i] = 0.0f; }

        #pragma unroll
        for (int c = 0; c < 4; ++c) {
            // B fragment from LDS: ch = 2c+hi, LDS row r = wv + 7 - ch.
            const float* rp = &sS[(wv + 7 - (2 * c + hi)) * PC + x0 + 6 + lo5];
            union { int i[4]; bf16x8 v; } bu;
            #pragma unroll
            for (int j = 0; j < 4; ++j) {
                float flo = rp[-(2 * j)];        // kx = 2j
                float fhi = rp[-(2 * j) - 1];    // kx = 2j+1
                asm("v_cvt_pk_bf16_f32 %0, %1, %2" : "=v"(bu.i[j]) : "v"(flo), "v"(fhi));
            }
            acc0 = __builtin_amdgcn_mfma_f32_32x32x16_bf16(afrag[0][c], bu.v, acc0, 0, 0, 0);
            acc1 = __builtin_amdgcn_mfma_f32_32x32x16_bf16(afrag[1][c], bu.v, acc1, 0, 0, 0);
        }

        // C/D layout: col = lo5 (pixel), row = (r&3) + 8*(r>>2) + 4*hi (oc)
        #pragma unroll
        for (int r = 0; r < 16; ++r) {
            const int row = (r & 3) + 8 * (r >> 2) + 4 * hi;
            outb[(size_t)row        * HWn + x0 + lo5] = acc0[r];
            outb[(size_t)(32 + row) * HWn + x0 + lo5] = acc1[r];
        }
    }
}

extern "C" void kernel_launch(void* const* d_in, const int* in_sizes, int n_in,
                              void* d_out, int out_size, void* d_ws, size_t ws_size,
                              hipStream_t stream) {
    const float* x = (const float*)d_in[0];   // [16,64,224,224] f32
    const float* K = (const float*)d_in[1];   // [64,64,7,7] f32
    float* out = (float*)d_out;               // [16,64,224,224] f32
    float* Sp = (float*)d_ws + GUARD;         // padded S' with guard
    unsigned short* W = (unsigned short*)((char*)d_ws + WOFF);

    const int npix4 = B_ * HWn / 4;
    chan_sum_kernel<<<(npix4 + 255) / 256, 256, 0, stream>>>(x, Sp);

    wprep_kernel<<<16, 256, 0, stream>>>(K, W);

    dim3 g2(112, 16);
    conv_mfma<<<g2, 128, 0, stream>>>(Sp, W, out);
}

// Round 20
// 76.402 us; speedup vs baseline: 3.7480x; 1.0343x over previous
//
#include <hip/hip_runtime.h>
#include <hip/hip_bf16.h>

#define Hn 224
#define HWn (224*224)
#define B_ 16
#define CIN_ 64
#define COUT_ 64
#define PR 230            // padded rows: 2 top + 224 + 4 bottom
#define PC 240            // padded row stride in floats
#define PHW (PR*PC)
#define GUARD 1024        // floats of guard before Sp (covers row -1 reads)
#define WOFF (4*1024*1024) // byte offset of W' in d_ws

typedef __attribute__((ext_vector_type(4)))  float f32x4;
typedef __attribute__((ext_vector_type(8)))  short bf16x8;
typedef __attribute__((ext_vector_type(16))) float f32x16;

// Kernel 1 (merged): blocks 0..783 = channel-sum into padded S' with inline
// halos (nt x-loads — R12 win); blocks 784..799 = W' prep (bf16, k=ky*8+kx).
__global__ __launch_bounds__(256) void chan_sum_kernel(const float* __restrict__ x,
                                                       float* __restrict__ Sp,
                                                       const float* __restrict__ K,
                                                       unsigned short* __restrict__ W) {
    if (blockIdx.x >= 784) {            // ---- wprep tail blocks ----
        int i = (blockIdx.x - 784) * 256 + threadIdx.x;   // 0..4095
        int oc = i >> 6, kk = i & 63;
        int ky = kk >> 3, kx = kk & 7;
        float v = (ky < 7 && kx < 7) ? K[(size_t)oc * (CIN_ * 49) + ky * 7 + kx] : 0.0f;
        __hip_bfloat16 h = __float2bfloat16(v);
        W[i] = *(unsigned short*)&h;
        return;
    }

    int idx = blockIdx.x * 256 + threadIdx.x;   // < 200704 exactly
    const int s4 = HWn / 4;
    int b  = idx / s4;
    int p4 = idx - b * s4;
    const f32x4* xb = (const f32x4*)x + (size_t)b * CIN_ * s4 + p4;

    f32x4 a0 = __builtin_nontemporal_load(xb + 0 * s4);
    f32x4 a1 = __builtin_nontemporal_load(xb + 1 * s4);
    f32x4 a2 = __builtin_nontemporal_load(xb + 2 * s4);
    f32x4 a3 = __builtin_nontemporal_load(xb + 3 * s4);
    #pragma unroll 4
    for (int c = 4; c < CIN_; c += 4) {
        a0 += __builtin_nontemporal_load(xb + (size_t)(c + 0) * s4);
        a1 += __builtin_nontemporal_load(xb + (size_t)(c + 1) * s4);
        a2 += __builtin_nontemporal_load(xb + (size_t)(c + 2) * s4);
        a3 += __builtin_nontemporal_load(xb + (size_t)(c + 3) * s4);
    }
    f32x4 r = (a0 + a1) + (a2 + a3);
    float v0 = r.x, v1 = r.y, v2 = r.z, v3 = r.w;

    int y  = p4 / 56;                 // 0..223
    int x0 = (p4 - y * 56) * 4;       // 0..220 step 4
    float* Sb = Sp + (size_t)b * PHW;

    float* dst = Sb + (size_t)(y + 2) * PC + 2 + x0;
    dst[0] = v0; dst[1] = v1; dst[2] = v2; dst[3] = v3;

    if (y < 4) {
        float* d = Sb + (size_t)(y + 226) * PC + 2 + x0;
        d[0] = v0; d[1] = v1; d[2] = v2; d[3] = v3;
    }
    if (y >= 222) {
        float* d = Sb + (size_t)(y - 222) * PC + 2 + x0;
        d[0] = v0; d[1] = v1; d[2] = v2; d[3] = v3;
    }
    if (x0 == 0) {
        float* d = Sb + (size_t)(y + 2) * PC + 226;
        d[0] = v0; d[1] = v1; d[2] = v2; d[3] = v3;
        if (y < 4) {
            float* e = Sb + (size_t)(y + 226) * PC + 226;
            e[0] = v0; e[1] = v1; e[2] = v2; e[3] = v3;
        }
        if (y >= 222) {
            float* e = Sb + (size_t)(y - 222) * PC + 226;
            e[0] = v0; e[1] = v1; e[2] = v2; e[3] = v3;
        }
    }
    if (x0 == 220) {                   // x 222,223 live in lanes v2,v3
        float* d = Sb + (size_t)(y + 2) * PC;
        d[0] = v2; d[1] = v3;
        if (y < 4) {
            float* e = Sb + (size_t)(y + 226) * PC;
            e[0] = v2; e[1] = v3;
        }
        if (y >= 222) {
            float* e = Sb + (size_t)(y - 222) * PC;
            e[0] = v2; e[1] = v3;
        }
    }
}

// Conv via MFMA — R19 LDS-staged body, widened: 256 threads = 4 waves =
// 4 output rows per block; stage 11 rows (yg*4-1 .. yg*4+9) once.
// Staging redundancy 4.5x -> 2.75x, half the blocks/barriers/A-prologues.
__global__ __launch_bounds__(256) void conv_mfma(const float* __restrict__ Sp,
                                                 const unsigned short* __restrict__ W,
                                                 float* __restrict__ out) {
    __shared__ float sS[11 * PC];        // 10.56 KB

    const int yg = blockIdx.x;           // 0..55
    const int b  = blockIdx.y;           // 0..15
    const int wv = threadIdx.x >> 6;     // 0..3
    const int l  = threadIdx.x & 63;
    const int y   = yg * 4 + wv;
    const int lo5 = l & 31;
    const int hi  = l >> 5;

    // stage 11 padded rows (row -1 falls in guard for yg==0: garbage x 0-weight)
    {
        const float* src = Sp + (size_t)b * PHW + (size_t)(yg * 4 - 1) * PC;
        for (int i = threadIdx.x; i < 11 * (PC / 4); i += 256) {
            int r = i / (PC / 4), c4 = i - r * (PC / 4);
            *(f32x4*)&sS[r * PC + c4 * 4] =
                *(const f32x4*)(src + (size_t)r * PC + c4 * 4);
        }
    }

    // A fragments: lane holds A[m=lo5][k = c*16 + hi*8 + j], j=0..7 (16B each)
    bf16x8 afrag[2][4];
    #pragma unroll
    for (int g = 0; g < 2; ++g)
        #pragma unroll
        for (int c = 0; c < 4; ++c)
            afrag[g][c] = *(const bf16x8*)(W + ((g * 32 + lo5) * 64 + c * 16 + hi * 8));

    __syncthreads();

    float* outb = out + (size_t)b * COUT_ * HWn + (size_t)y * Hn;

    for (int xt = 0; xt < 7; ++xt) {
        const int x0 = xt * 32;

        f32x16 acc0, acc1;
        #pragma unroll
        for (int i = 0; i < 16; ++i) { acc0[i] = 0.0f; acc1[i] = 0.0f; }

        #pragma unroll
        for (int c = 0; c < 4; ++c) {
            // B fragment from LDS: ch = 2c+hi, LDS row = wv + 7 - ch
            // (staging origin yg*4-1; y - yg*4 = wv).
            const float* rp = &sS[(wv + 7 - (2 * c + hi)) * PC + x0 + 6 + lo5];
            union { int i[4]; bf16x8 v; } bu;
            #pragma unroll
            for (int j = 0; j < 4; ++j) {
                float flo = rp[-(2 * j)];        // kx = 2j
                float fhi = rp[-(2 * j) - 1];    // kx = 2j+1
                asm("v_cvt_pk_bf16_f32 %0, %1, %2" : "=v"(bu.i[j]) : "v"(flo), "v"(fhi));
            }
            acc0 = __builtin_amdgcn_mfma_f32_32x32x16_bf16(afrag[0][c], bu.v, acc0, 0, 0, 0);
            acc1 = __builtin_amdgcn_mfma_f32_32x32x16_bf16(afrag[1][c], bu.v, acc1, 0, 0, 0);
        }

        // C/D layout: col = lo5 (pixel), row = (r&3) + 8*(r>>2) + 4*hi (oc)
        #pragma unroll
        for (int r = 0; r < 16; ++r) {
            const int row = (r & 3) + 8 * (r >> 2) + 4 * hi;
            outb[(size_t)row        * HWn + x0 + lo5] = acc0[r];
            outb[(size_t)(32 + row) * HWn + x0 + lo5] = acc1[r];
        }
    }
}

extern "C" void kernel_launch(void* const* d_in, const int* in_sizes, int n_in,
                              void* d_out, int out_size, void* d_ws, size_t ws_size,
                              hipStream_t stream) {
    const float* x = (const float*)d_in[0];   // [16,64,224,224] f32
    const float* K = (const float*)d_in[1];   // [64,64,7,7] f32
    float* out = (float*)d_out;               // [16,64,224,224] f32
    float* Sp = (float*)d_ws + GUARD;         // padded S' with guard
    unsigned short* W = (unsigned short*)((char*)d_ws + WOFF);

    // 784 pixel blocks + 16 wprep blocks in one launch
    chan_sum_kernel<<<800, 256, 0, stream>>>(x, Sp, K, W);

    dim3 g2(56, 16);
    conv_mfma<<<g2, 256, 0, stream>>>(Sp, W, out);
}